// Round 7
// baseline (773.335 us; speedup 1.0000x reference)
//
#include <hip/hip_runtime.h>

#define HL 96
#define WL 96
#define HO 384
#define WO 384
#define NPIX (2*HO*WO)           // 294912 output pixels (B=2)
#define FEAT_ELEMS ((size_t)2*64*HL*WL)  // 1179648
#define PLANE (HL*WL)            // 9216

typedef unsigned short us4 __attribute__((ext_vector_type(4)));
typedef unsigned short us8 __attribute__((ext_vector_type(8)));
typedef __bf16         b8  __attribute__((ext_vector_type(8)));
typedef float          f32x4 __attribute__((ext_vector_type(4)));

__device__ __forceinline__ unsigned short f2b(float x) {
  unsigned u = __builtin_bit_cast(unsigned, x);
  unsigned r = (u + 0x7FFFu + ((u >> 16) & 1u)) >> 16;
  return (unsigned short)r;
}

__device__ __forceinline__ f32x4 MF(us8 a, us8 b, f32x4 c) {
  return __builtin_amdgcn_mfma_f32_16x16x32_bf16(
      __builtin_bit_cast(b8, a), __builtin_bit_cast(b8, b), c, 0, 0, 0);
}

// ---------------------------------------------------------------------------
// Scalar-weight direct conv (known good)
// ---------------------------------------------------------------------------
template<int CIN, int COPT, bool RELU, bool RES>
__global__ __launch_bounds__(256) void conv_s_k(
    const float* __restrict__ in, const float* __restrict__ wP,
    const float* __restrict__ bias, const float* __restrict__ res,
    float* __restrict__ out)
{
  const int t   = threadIdx.x;
  const int p   = blockIdx.x * 256 + t;
  const int co0 = blockIdx.y * COPT;
  const int b   = blockIdx.z;
  const int x   = p % WL;
  const bool xl = (x == 0), xr = (x == WL - 1);

  float acc[COPT];
  #pragma unroll
  for (int j = 0; j < COPT; ++j) acc[j] = bias[co0 + j];

  int  ic[3]; bool yv[3];
  int  im[3], ip[3];
  #pragma unroll
  for (int ky = 0; ky < 3; ++ky) {
    int pr = p + (ky - 1) * WL;
    yv[ky] = ((unsigned)pr < (unsigned)PLANE);
    ic[ky] = yv[ky] ? pr : 0;
    im[ky] = ic[ky] - 1; if (im[ky] < 0) im[ky] = 0;
    ip[ky] = ic[ky] + 1; if (ip[ky] > PLANE - 1) ip[ky] = PLANE - 1;
  }

  const float* inb = in + (size_t)b * CIN * PLANE;

  #pragma unroll 2
  for (int ci = 0; ci < CIN; ++ci) {
    const float* pl = inb + (size_t)ci * PLANE;
    #pragma unroll
    for (int ky = 0; ky < 3; ++ky) {
      float am = pl[im[ky]];
      float a0 = pl[ic[ky]];
      float ap = pl[ip[ky]];
      if (!yv[ky]) { am = 0.f; a0 = 0.f; ap = 0.f; }
      if (xl) am = 0.f;
      if (xr) ap = 0.f;
      const float* wrow = wP + (size_t)(ci * 9 + ky * 3) * 64 + co0;
      #pragma unroll
      for (int j = 0; j < COPT; ++j) acc[j] += am * wrow[j];
      #pragma unroll
      for (int j = 0; j < COPT; ++j) acc[j] += a0 * wrow[64 + j];
      #pragma unroll
      for (int j = 0; j < COPT; ++j) acc[j] += ap * wrow[128 + j];
    }
  }

  size_t ob = ((size_t)b * 64 + co0) * PLANE + p;
  #pragma unroll
  for (int j = 0; j < COPT; ++j) {
    float v = acc[j];
    if (RELU) v = fmaxf(v, 0.f);
    if (RES)  v += res[ob + (size_t)j * PLANE];
    out[ob + (size_t)j * PLANE] = v;
  }
}

__global__ __launch_bounds__(256) void prep_convw_k(const float* __restrict__ src,
                                                    float* __restrict__ dst, int cin)
{
  int idx = blockIdx.x * 256 + threadIdx.x;
  int tot = cin * 9 * 64;
  if (idx >= tot) return;
  int co = idx % 64; int r = idx / 64;
  int ci = r / 9, tap = r % 9;
  dst[idx] = src[((size_t)co * cin + ci) * 9 + tap];
}

__global__ __launch_bounds__(256) void nchw_to_nhwc_k(const float* __restrict__ in,
                                                      float* __restrict__ out)
{
  __shared__ float s[64][65];
  const int b = blockIdx.y;
  const int pix0 = blockIdx.x * 64;
  const int t = threadIdx.x;
  #pragma unroll
  for (int cc = 0; cc < 16; ++cc) {
    int co = cc * 4 + (t >> 6);
    int px = t & 63;
    s[px][co] = in[((size_t)b * 64 + co) * PLANE + pix0 + px];
  }
  __syncthreads();
  #pragma unroll
  for (int pp = 0; pp < 16; ++pp) {
    int px = pp * 4 + (t >> 6);
    int co = t & 63;
    out[((size_t)b * PLANE + pix0 + px) * 64 + co] = s[px][co];
  }
}

__global__ __launch_bounds__(256) void prep_wt_k(const float* __restrict__ src,
    unsigned short* __restrict__ dst, int K, int N, int Kpad, int Npad)
{
  int idx = blockIdx.x * 256 + threadIdx.x;
  if (idx >= Kpad * Npad) return;
  int n = idx / Kpad, k = idx - n * Kpad;
  float v = (k < K && n < N) ? src[(size_t)k * N + n] : 0.f;
  dst[idx] = f2b(v);
}

// ---------------------------------------------------------------------------
// fp32 64-wide layer (classifier; LDS src/dst, no private arrays)
// ---------------------------------------------------------------------------
__device__ __forceinline__ void layer64(const float* src, int sstride,
    const float* __restrict__ W, const float* __restrict__ B,
    float* dst, int dstride, int K, bool relu, int t)
{
  const int p  = t >> 3;
  const int c0 = (t & 7) << 3;
  float acc[8];
  #pragma unroll
  for (int j = 0; j < 8; ++j) acc[j] = B[c0 + j];
  const float* s = src + p * sstride;
  for (int k = 0; k < K; k += 4) {
    float4 a4 = *(const float4*)(s + k);
    float av[4] = {a4.x, a4.y, a4.z, a4.w};
    #pragma unroll
    for (int kk = 0; kk < 4; ++kk) {
      float a = av[kk];
      float4 w0 = *(const float4*)&W[(size_t)(k + kk) * 64 + c0];
      float4 w1 = *(const float4*)&W[(size_t)(k + kk) * 64 + c0 + 4];
      acc[0] += a * w0.x; acc[1] += a * w0.y; acc[2] += a * w0.z; acc[3] += a * w0.w;
      acc[4] += a * w1.x; acc[5] += a * w1.y; acc[6] += a * w1.z; acc[7] += a * w1.w;
    }
  }
  float* d = dst + p * dstride + c0;
  #pragma unroll
  for (int j = 0; j < 8; ++j) d[j] = relu ? fmaxf(acc[j], 0.f) : acc[j];
}

// ---------------------------------------------------------------------------
// MFMA helpers (verified geometry, M=64)
// ---------------------------------------------------------------------------
template<int NT, int KT>
__device__ __forceinline__ void mfma_compute(
    const unsigned short* __restrict__ aBase, int AS,
    const unsigned short* __restrict__ WT, int Kpad,
    int n0, int lane, f32x4 (&acc)[4][NT])
{
  const int lr = lane & 15;
  const int lc = lane >> 4;
  #pragma unroll
  for (int m = 0; m < 4; ++m)
    #pragma unroll
    for (int j = 0; j < NT; ++j) acc[m][j] = (f32x4){0.f, 0.f, 0.f, 0.f};

  const unsigned short* aP = aBase + lr * AS + lc * 8;
  const unsigned short* bP = WT + (size_t)(n0 + lr) * Kpad + lc * 8;

  constexpr int KCH = (KT >= 4) ? 4 : KT;
  #pragma unroll
  for (int kc = 0; kc < KT; kc += KCH) {
    us8 breg[KCH][NT];
    #pragma unroll
    for (int kk = 0; kk < KCH; ++kk)
      #pragma unroll
      for (int j = 0; j < NT; ++j)
        breg[kk][j] = *(const us8*)(bP + (size_t)j * 16 * Kpad + (kc + kk) * 32);
    #pragma unroll
    for (int kk = 0; kk < KCH; ++kk) {
      us8 a0[4];
      #pragma unroll
      for (int m = 0; m < 4; ++m)
        a0[m] = *(const us8*)(aP + (m * 16) * AS + (kc + kk) * 32);
      #pragma unroll
      for (int m = 0; m < 4; ++m)
        #pragma unroll
        for (int j = 0; j < NT; ++j)
          acc[m][j] = MF(a0[m], breg[kk][j], acc[m][j]);
    }
  }
}

template<int NT, bool RELU>
__device__ __forceinline__ void mfma_store(
    const f32x4 (&acc)[4][NT], const float* __restrict__ bias,
    unsigned short* __restrict__ dBase, int DS, int dCol0, int n0, int lane)
{
  const int lr = lane & 15;
  const int lc = lane >> 4;
  #pragma unroll
  for (int j = 0; j < NT; ++j) {
    int n = n0 + j * 16 + lr;
    float bv = bias[n];
    #pragma unroll
    for (int m = 0; m < 4; ++m)
      #pragma unroll
      for (int r = 0; r < 4; ++r) {
        float v = acc[m][j][r] + bv;
        if (RELU) v = fmaxf(v, 0.f);
        dBase[(m * 16 + lc * 4 + r) * DS + dCol0 + n] = f2b(v);
      }
  }
}

template<int KT>
__device__ __forceinline__ void mfma_out3w(
    const unsigned short* __restrict__ aBase, int AS,
    const unsigned short* __restrict__ WT, int Kpad,
    const float* __restrict__ bias, float (*dst)[4], int mtile, int lane)
{
  const int lr = lane & 15;
  const int lc = lane >> 4;
  f32x4 acc = (f32x4){0.f, 0.f, 0.f, 0.f};
  const unsigned short* aP = aBase + (mtile * 16 + lr) * AS + lc * 8;
  const unsigned short* bP = WT + (size_t)lr * Kpad + lc * 8;

  constexpr int KCH = (KT >= 4) ? 4 : KT;
  #pragma unroll
  for (int kc = 0; kc < KT; kc += KCH) {
    us8 breg[KCH];
    #pragma unroll
    for (int kk = 0; kk < KCH; ++kk)
      breg[kk] = *(const us8*)(bP + (kc + kk) * 32);
    #pragma unroll
    for (int kk = 0; kk < KCH; ++kk) {
      us8 a = *(const us8*)(aP + (kc + kk) * 32);
      acc = MF(a, breg[kk], acc);
    }
  }
  if (lr < 3) {
    float bv = bias[lr];
    #pragma unroll
    for (int r = 0; r < 4; ++r)
      dst[mtile * 16 + lc * 4 + r][lr] = acc[r] + bv;
  }
}

// ---------------------------------------------------------------------------
// Shared helpers
// ---------------------------------------------------------------------------
__device__ __forceinline__ void nearest_idx(float gy, float gx, int& iy, int& ix)
{
  float fy = (gy + 1.f) * (HL * 0.5f) - 0.5f;
  float fx = (gx + 1.f) * (WL * 0.5f) - 0.5f;
  iy = min(max((int)floorf(fy + 0.5f), 0), HL - 1);
  ix = min(max((int)floorf(fx + 0.5f), 0), WL - 1);
}

__device__ __forceinline__ float bilinear_lr(const float* __restrict__ lrimg,
                                             int b, int ch, float gy, float gx)
{
  float x = (gx + 1.f) * (WL * 0.5f) - 0.5f;
  float y = (gy + 1.f) * (HL * 0.5f) - 0.5f;
  float xf = floorf(x), yf = floorf(y);
  float wx = x - xf, wy = y - yf;
  int x0i = min(max((int)xf,     0), WL - 1);
  int x1i = min(max((int)xf + 1, 0), WL - 1);
  int y0i = min(max((int)yf,     0), HL - 1);
  int y1i = min(max((int)yf + 1, 0), HL - 1);
  const float* img = lrimg + ((size_t)b * 3 + ch) * PLANE;
  float v00 = img[y0i * WL + x0i], v01 = img[y0i * WL + x1i];
  float v10 = img[y1i * WL + x0i], v11 = img[y1i * WL + x1i];
  return v00 * (1.f - wx) * (1.f - wy) + v01 * wx * (1.f - wy)
       + v10 * (1.f - wx) * wy + v11 * wx * wy;
}

// ---------------------------------------------------------------------------
// Pass 1 (v2): dense fp32 classifier via LDS (validated fused structure),
// then wave-ballot compaction into easy/hard lists. 32 px / 256-thr block.
// ---------------------------------------------------------------------------
__global__ __launch_bounds__(256, 4) void cls_gate_k(
    const float* __restrict__ featT, const float* __restrict__ coord,
    const float* __restrict__ cell,
    const float* __restrict__ cw1, const float* __restrict__ cb1,
    const float* __restrict__ cw2, const float* __restrict__ cb2,
    int* __restrict__ counters, unsigned* __restrict__ easyList,
    unsigned* __restrict__ hardList)
{
  __shared__ float sInpF[32][72];
  __shared__ float sCls[32][66];
  __shared__ int   sHard[32];

  const int t  = threadIdx.x;
  const int g0 = blockIdx.x * 32;

  // build fp32 inp rows in LDS (8 thr/px, 8 floats each)
  {
    const int p = t >> 3, q = t & 7;
    const int g = g0 + p;
    const int b = g / (HO * WO);
    const float gy = coord[(size_t)g * 2 + 0];
    const float gx = coord[(size_t)g * 2 + 1];
    int iy, ix; nearest_idx(gy, gx, iy, ix);
    const float* fp = featT + (((size_t)b * PLANE) + iy * WL + ix) * 64 + q * 8;
    float4 u0 = *(const float4*)fp;
    float4 u1 = *(const float4*)(fp + 4);
    *(float4*)&sInpF[p][q * 8]     = u0;
    *(float4*)&sInpF[p][q * 8 + 4] = u1;
    if (q == 0) {
      float cy = (2.f * iy + 1.f) / HL - 1.f;
      float cx = (2.f * ix + 1.f) / WL - 1.f;
      sInpF[p][64] = (gy - cy) * HL;
      sInpF[p][65] = (gx - cx) * WL;
      sInpF[p][66] = cell[(size_t)g * 2 + 0] * HL;
      sInpF[p][67] = cell[(size_t)g * 2 + 1] * WL;
    }
  }
  __syncthreads();

  layer64(&sInpF[0][0], 72, cw1, cb1, &sCls[0][0], 66, 68, true, t);
  __syncthreads();

  if (t < 32) {
    float l0 = cb2[0], l1 = cb2[1];
    for (int c = 0; c < 64; ++c) {
      float h = sCls[t][c];
      l0 += h * cw2[c * 2 + 0];
      l1 += h * cw2[c * 2 + 1];
    }
    sHard[t] = (l1 > l0) ? 1 : 0;
  }
  __syncthreads();

  if (t < 64) {
    bool hard = (t < 32) && (sHard[t] != 0);
    bool easy = (t < 32) && (sHard[t] == 0);
    unsigned long long mh = __ballot(hard);
    unsigned long long me = __ballot(easy);
    int nh = __popcll(mh), ne = __popcll(me);
    int baseH = 0, baseE = 0;
    if (t == 0) {
      baseH = atomicAdd(&counters[1], nh);
      baseE = atomicAdd(&counters[0], ne);
    }
    baseH = __shfl(baseH, 0);
    baseE = __shfl(baseE, 0);
    unsigned long long below = (1ull << t) - 1ull;
    if (hard)      hardList[baseH + __popcll(mh & below)] = (unsigned)(g0 + t);
    else if (easy) easyList[baseE + __popcll(me & below)] = (unsigned)(g0 + t);
  }
}

// ---------------------------------------------------------------------------
// Gather helper: build bf16 inp row for pixel g into sInpB[p][0..103]
// ---------------------------------------------------------------------------
__device__ __forceinline__ void build_inp_row(
    const float* __restrict__ featT, const float* __restrict__ coord,
    const float* __restrict__ cell, unsigned g, int p, int q8,
    unsigned short (*sInpB)[104])
{
  int b = g / (HO * WO);
  float gy = coord[(size_t)g * 2 + 0];
  float gx = coord[(size_t)g * 2 + 1];
  int iy, ix; nearest_idx(gy, gx, iy, ix);
  const float* fpt = featT + (((size_t)b * PLANE) + iy * WL + ix) * 64 + q8 * 8;
  float4 u0 = *(const float4*)fpt;
  float4 u1 = *(const float4*)(fpt + 4);
  us8 pk;
  pk[0]=f2b(u0.x); pk[1]=f2b(u0.y); pk[2]=f2b(u0.z); pk[3]=f2b(u0.w);
  pk[4]=f2b(u1.x); pk[5]=f2b(u1.y); pk[6]=f2b(u1.z); pk[7]=f2b(u1.w);
  *(us8*)&sInpB[p][q8 * 8] = pk;
  if (q8 == 0) {
    float cy = (2.f * iy + 1.f) / HL - 1.f;
    float cx = (2.f * ix + 1.f) / WL - 1.f;
    float e0 = (gy - cy) * HL, e1 = (gx - cx) * WL;
    float e2 = cell[(size_t)g * 2 + 0] * HL, e3 = cell[(size_t)g * 2 + 1] * WL;
    us4 pe; pe[0]=f2b(e0); pe[1]=f2b(e1); pe[2]=f2b(e2); pe[3]=f2b(e3);
    *(us4*)&sInpB[p][64] = pe;
  }
  if (q8 == 1) {
    us4 z = (us4){0,0,0,0};
    #pragma unroll
    for (int c = 0; c < 9; ++c) *(us4*)&sInpB[p][68 + c * 4] = z;
  }
}

// ---------------------------------------------------------------------------
// Pass 2: light MLP over easy list (64 px / block, 256 thr)
// ---------------------------------------------------------------------------
__global__ __launch_bounds__(256, 4) void light_k(
    const float* __restrict__ featT, const float* __restrict__ coord,
    const float* __restrict__ cell,  const float* __restrict__ lrimg,
    const float* __restrict__ lb1, const float* __restrict__ lb2,
    const float* __restrict__ lb3,
    const unsigned short* __restrict__ lw1T, const unsigned short* __restrict__ lw2T,
    const unsigned short* __restrict__ lw3T,
    const int* __restrict__ counters, const unsigned* __restrict__ list,
    float* __restrict__ out)
{
  const int nE = counters[0];
  const int g0 = blockIdx.x * 64;
  if (g0 >= nE) return;

  __shared__ unsigned short sInpB[64][104];
  __shared__ unsigned short sL1[64][72];
  __shared__ unsigned short sL2[64][72];
  __shared__ float sP[64][4];
  __shared__ unsigned sIdx[64];

  const int t = threadIdx.x, lane = t & 63, w = t >> 6;

  {
    const int p = t >> 2, q = t & 3;
    int i = g0 + p; if (i > nE - 1) i = nE - 1;
    unsigned g = list[i];
    if (q == 0) sIdx[p] = g;
    build_inp_row(featT, coord, cell, g, p, q * 2,     sInpB);
    build_inp_row(featT, coord, cell, g, p, q * 2 + 1, sInpB);
  }
  __syncthreads();

  { f32x4 acc[4][1];
    mfma_compute<1, 3>(&sInpB[0][0], 104, lw1T, 96, w * 16, lane, acc);
    mfma_store<1, true>(acc, lb1, &sL1[0][0], 72, 0, w * 16, lane); }
  __syncthreads();
  { f32x4 acc[4][1];
    mfma_compute<1, 2>(&sL1[0][0], 72, lw2T, 64, w * 16, lane, acc);
    mfma_store<1, true>(acc, lb2, &sL2[0][0], 72, 0, w * 16, lane); }
  __syncthreads();
  mfma_out3w<2>(&sL2[0][0], 72, lw3T, 64, lb3, sP, w, lane);
  __syncthreads();

  if (t < 192) {
    int p = t / 3, ch = t % 3;
    int i = g0 + p;
    if (i < nE) {
      unsigned g = sIdx[p];
      int b = g / (HO * WO);
      int rem = g % (HO * WO);
      int oy = rem / WO, ox = rem % WO;
      float gy = coord[(size_t)g * 2 + 0];
      float gx = coord[(size_t)g * 2 + 1];
      float v = bilinear_lr(lrimg, b, ch, gy, gx);
      out[(((size_t)b * 3 + ch) * HO + oy) * WO + ox] = sP[p][ch] + v;
    }
  }
}

// ---------------------------------------------------------------------------
// Pass 3: heavy MLP over hard list (64 px / block, 512 thr)
// ---------------------------------------------------------------------------
__global__ __launch_bounds__(512, 4) void heavy_k(
    const float* __restrict__ featT, const float* __restrict__ coord,
    const float* __restrict__ cell,  const float* __restrict__ lrimg,
    const float* __restrict__ hb1, const float* __restrict__ hmb,
    const float* __restrict__ hbo,
    const unsigned short* __restrict__ hw1T, const unsigned short* __restrict__ hm0T,
    const unsigned short* __restrict__ hm1T, const unsigned short* __restrict__ hwoT,
    const int* __restrict__ counters, const unsigned* __restrict__ list,
    float* __restrict__ out)
{
  const int nH = counters[1];
  const int g0 = blockIdx.x * 64;
  if (g0 >= nH) return;

  __shared__ unsigned short sAct[64][264];
  __shared__ unsigned short sInpB[64][104];
  __shared__ float sP[64][4];
  __shared__ unsigned sIdx[64];

  const int t = threadIdx.x, lane = t & 63, w = t >> 6;

  {
    const int p = t >> 3, q = t & 7;
    int i = g0 + p; if (i > nH - 1) i = nH - 1;
    unsigned g = list[i];
    if (q == 0) sIdx[p] = g;
    build_inp_row(featT, coord, cell, g, p, q, sInpB);
  }
  __syncthreads();

  { f32x4 acc[4][2];
    mfma_compute<2, 3>(&sInpB[0][0], 104, hw1T, 96, w * 32, lane, acc);
    mfma_store<2, true>(acc, hb1, &sAct[0][0], 264, 0, w * 32, lane); }
  __syncthreads();
  { f32x4 acc[4][2];
    mfma_compute<2, 8>(&sAct[0][0], 264, hm0T, 256, w * 32, lane, acc);
    __syncthreads();
    mfma_store<2, true>(acc, hmb, &sAct[0][0], 264, 0, w * 32, lane); }
  __syncthreads();
  { f32x4 acc[4][2];
    mfma_compute<2, 8>(&sAct[0][0], 264, hm1T, 256, w * 32, lane, acc);
    __syncthreads();
    mfma_store<2, true>(acc, hmb + 256, &sAct[0][0], 264, 0, w * 32, lane); }
  __syncthreads();
  if (w < 4) mfma_out3w<8>(&sAct[0][0], 264, hwoT, 256, hbo, sP, w, lane);
  __syncthreads();

  if (t < 192) {
    int p = t / 3, ch = t % 3;
    int i = g0 + p;
    if (i < nH) {
      unsigned g = sIdx[p];
      int b = g / (HO * WO);
      int rem = g % (HO * WO);
      int oy = rem / WO, ox = rem % WO;
      float gy = coord[(size_t)g * 2 + 0];
      float gx = coord[(size_t)g * 2 + 1];
      float v = bilinear_lr(lrimg, b, ch, gy, gx);
      out[(((size_t)b * 3 + ch) * HO + oy) * WO + ox] = sP[p][ch] + v;
    }
  }
}

__global__ void finalize_k(const int* __restrict__ counters, float* __restrict__ out)
{
  out[(size_t)NPIX * 3] = (float)(counters[0]) / (float)NPIX;
}

// ---------------------------------------------------------------------------
extern "C" void kernel_launch(void* const* d_in, const int* in_sizes, int n_in,
                              void* d_out, int out_size, void* d_ws, size_t ws_size,
                              hipStream_t stream)
{
  const float* lr       = (const float*)d_in[0];
  const float* coord    = (const float*)d_in[1];
  const float* cell     = (const float*)d_in[2];
  const float* enc_w_in = (const float*)d_in[3];
  const float* enc_b_in = (const float*)d_in[4];
  const float* enc_rw   = (const float*)d_in[5];
  const float* enc_rb   = (const float*)d_in[6];
  const float* cw1      = (const float*)d_in[7];
  const float* cb1      = (const float*)d_in[8];
  const float* cw2      = (const float*)d_in[9];
  const float* cb2      = (const float*)d_in[10];
  const float* lw1      = (const float*)d_in[11];
  const float* lb1      = (const float*)d_in[12];
  const float* lw2      = (const float*)d_in[13];
  const float* lb2      = (const float*)d_in[14];
  const float* lw3      = (const float*)d_in[15];
  const float* lb3      = (const float*)d_in[16];
  const float* hw1      = (const float*)d_in[17];
  const float* hb1      = (const float*)d_in[18];
  const float* hmw      = (const float*)d_in[19];
  const float* hmb      = (const float*)d_in[20];
  const float* hwo      = (const float*)d_in[21];
  const float* hbo      = (const float*)d_in[22];
  float* out = (float*)d_out;

  char* ws = (char*)d_ws;
  float* xA    = (float*)(ws + 1024);
  float* tmp   = xA  + FEAT_ELEMS;
  float* xB    = tmp + FEAT_ELEMS;
  float* featT = tmp;                 // aliases tmp (free after last res conv)
  unsigned short* wb = (unsigned short*)(xB + FEAT_ELEMS);
  unsigned short* lw1T = wb;              // 64*96
  unsigned short* lw2T = lw1T + 64*96;    // 64*64
  unsigned short* lw3T = lw2T + 64*64;    // 16*64
  unsigned short* hw1T = lw3T + 16*64;    // 256*96
  unsigned short* hm0T = hw1T + 256*96;   // 256*256
  unsigned short* hm1T = hm0T + 65536;    // 256*256
  unsigned short* hwoT = hm1T + 65536;    // 16*256
  const size_t nb16 = 64*96 + 64*64 + 16*64 + 256*96 + 2*65536 + 16*256; // 171008
  float* cwIn  = (float*)(wb + nb16);     // 27*64 = 1728
  float* cwRes = cwIn + 1728;             // 8 * 36864
  size_t need = 1024 + 3 * FEAT_ELEMS * sizeof(float)
              + nb16 * 2 + (1728 + 8 * 36864) * sizeof(float);
  if (ws_size < need) return;

  // lists/counters alias xB (free after final residual conv)
  int*      counters = (int*)xB;
  unsigned* easyList = (unsigned*)(xB + 16);
  unsigned* hardList = easyList + NPIX;

  auto prep = [&](const float* s, unsigned short* d, int K, int N, int Kp, int Np) {
    int tot = Kp * Np;
    prep_wt_k<<<(tot + 255) / 256, 256, 0, stream>>>(s, d, K, N, Kp, Np);
  };
  prep(lw1, lw1T, 68, 64, 96, 64);
  prep(lw2, lw2T, 64, 64, 64, 64);
  prep(lw3, lw3T, 64, 3, 64, 16);
  prep(hw1, hw1T, 68, 256, 96, 256);
  prep(hmw,         hm0T, 256, 256, 256, 256);
  prep(hmw + 65536, hm1T, 256, 256, 256, 256);
  prep(hwo, hwoT, 256, 3, 256, 16);

  prep_convw_k<<<(1728 + 255) / 256, 256, 0, stream>>>(enc_w_in, cwIn, 3);
  for (int l = 0; l < 8; ++l)
    prep_convw_k<<<(36864 + 255) / 256, 256, 0, stream>>>(
        enc_rw + (size_t)l * 36864, cwRes + (size_t)l * 36864, 64);

  // --- encoder (fp32; ends with feat in xA) ---
  dim3 cgrid(36, 16, 2);
  conv_s_k<3, 4, false, false><<<cgrid, 256, 0, stream>>>(lr, cwIn, enc_b_in, nullptr, xA);

  float* cur = xA; float* oth = xB;
  for (int i = 0; i < 4; ++i) {
    const float* wp0 = cwRes + (size_t)(2 * i)     * 36864;
    const float* wp1 = cwRes + (size_t)(2 * i + 1) * 36864;
    const float* b0 = enc_rb + i * 128;
    const float* b1 = b0 + 64;
    conv_s_k<64, 4, true,  false><<<cgrid, 256, 0, stream>>>(cur, wp0, b0, nullptr, tmp);
    conv_s_k<64, 4, false, true ><<<cgrid, 256, 0, stream>>>(tmp, wp1, b1, cur, oth);
    float* sw2 = cur; cur = oth; oth = sw2;
  }
  // cur == xA here -> xB free for lists

  nchw_to_nhwc_k<<<dim3(144, 2), 256, 0, stream>>>(cur, featT);

  hipMemsetAsync(counters, 0, 16, stream);

  cls_gate_k<<<NPIX / 32, 256, 0, stream>>>(featT, coord, cell,
      cw1, cb1, cw2, cb2, counters, easyList, hardList);

  light_k<<<NPIX / 64, 256, 0, stream>>>(featT, coord, cell, lr,
      lb1, lb2, lb3, lw1T, lw2T, lw3T, counters, easyList, out);

  heavy_k<<<NPIX / 64, 512, 0, stream>>>(featT, coord, cell, lr,
      hb1, hmb, hbo, hw1T, hm0T, hm1T, hwoT, counters, hardList, out);

  finalize_k<<<1, 1, 0, stream>>>(counters, out);
}

// Round 8
// 690.143 us; speedup vs baseline: 1.1205x; 1.1205x over previous
//
#include <hip/hip_runtime.h>

#define HL 96
#define WL 96
#define HO 384
#define WO 384
#define NPIX (2*HO*WO)           // 294912 output pixels (B=2)
#define FEAT_ELEMS ((size_t)2*64*HL*WL)  // 1179648
#define PLANE (HL*WL)            // 9216

typedef unsigned short us4 __attribute__((ext_vector_type(4)));
typedef unsigned short us8 __attribute__((ext_vector_type(8)));
typedef __bf16         b8  __attribute__((ext_vector_type(8)));
typedef float          f32x4 __attribute__((ext_vector_type(4)));

__device__ __forceinline__ unsigned short f2b(float x) {
  unsigned u = __builtin_bit_cast(unsigned, x);
  unsigned r = (u + 0x7FFFu + ((u >> 16) & 1u)) >> 16;
  return (unsigned short)r;
}

__device__ __forceinline__ f32x4 MF(us8 a, us8 b, f32x4 c) {
  return __builtin_amdgcn_mfma_f32_16x16x32_bf16(
      __builtin_bit_cast(b8, a), __builtin_bit_cast(b8, b), c, 0, 0, 0);
}

// ---------------------------------------------------------------------------
// Scalar-weight direct conv (known good)
// ---------------------------------------------------------------------------
template<int CIN, int COPT, bool RELU, bool RES>
__global__ __launch_bounds__(256) void conv_s_k(
    const float* __restrict__ in, const float* __restrict__ wP,
    const float* __restrict__ bias, const float* __restrict__ res,
    float* __restrict__ out)
{
  const int t   = threadIdx.x;
  const int p   = blockIdx.x * 256 + t;
  const int co0 = blockIdx.y * COPT;
  const int b   = blockIdx.z;
  const int x   = p % WL;
  const bool xl = (x == 0), xr = (x == WL - 1);

  float acc[COPT];
  #pragma unroll
  for (int j = 0; j < COPT; ++j) acc[j] = bias[co0 + j];

  int  ic[3]; bool yv[3];
  int  im[3], ip[3];
  #pragma unroll
  for (int ky = 0; ky < 3; ++ky) {
    int pr = p + (ky - 1) * WL;
    yv[ky] = ((unsigned)pr < (unsigned)PLANE);
    ic[ky] = yv[ky] ? pr : 0;
    im[ky] = ic[ky] - 1; if (im[ky] < 0) im[ky] = 0;
    ip[ky] = ic[ky] + 1; if (ip[ky] > PLANE - 1) ip[ky] = PLANE - 1;
  }

  const float* inb = in + (size_t)b * CIN * PLANE;

  #pragma unroll 2
  for (int ci = 0; ci < CIN; ++ci) {
    const float* pl = inb + (size_t)ci * PLANE;
    #pragma unroll
    for (int ky = 0; ky < 3; ++ky) {
      float am = pl[im[ky]];
      float a0 = pl[ic[ky]];
      float ap = pl[ip[ky]];
      if (!yv[ky]) { am = 0.f; a0 = 0.f; ap = 0.f; }
      if (xl) am = 0.f;
      if (xr) ap = 0.f;
      const float* wrow = wP + (size_t)(ci * 9 + ky * 3) * 64 + co0;
      #pragma unroll
      for (int j = 0; j < COPT; ++j) acc[j] += am * wrow[j];
      #pragma unroll
      for (int j = 0; j < COPT; ++j) acc[j] += a0 * wrow[64 + j];
      #pragma unroll
      for (int j = 0; j < COPT; ++j) acc[j] += ap * wrow[128 + j];
    }
  }

  size_t ob = ((size_t)b * 64 + co0) * PLANE + p;
  #pragma unroll
  for (int j = 0; j < COPT; ++j) {
    float v = acc[j];
    if (RELU) v = fmaxf(v, 0.f);
    if (RES)  v += res[ob + (size_t)j * PLANE];
    out[ob + (size_t)j * PLANE] = v;
  }
}

__global__ __launch_bounds__(256) void prep_convw_k(const float* __restrict__ src,
                                                    float* __restrict__ dst, int cin)
{
  int idx = blockIdx.x * 256 + threadIdx.x;
  int tot = cin * 9 * 64;
  if (idx >= tot) return;
  int co = idx % 64; int r = idx / 64;
  int ci = r / 9, tap = r % 9;
  dst[idx] = src[((size_t)co * cin + ci) * 9 + tap];
}

__global__ __launch_bounds__(256) void nchw_to_nhwc_k(const float* __restrict__ in,
                                                      float* __restrict__ out)
{
  __shared__ float s[64][65];
  const int b = blockIdx.y;
  const int pix0 = blockIdx.x * 64;
  const int t = threadIdx.x;
  #pragma unroll
  for (int cc = 0; cc < 16; ++cc) {
    int co = cc * 4 + (t >> 6);
    int px = t & 63;
    s[px][co] = in[((size_t)b * 64 + co) * PLANE + pix0 + px];
  }
  __syncthreads();
  #pragma unroll
  for (int pp = 0; pp < 16; ++pp) {
    int px = pp * 4 + (t >> 6);
    int co = t & 63;
    out[((size_t)b * PLANE + pix0 + px) * 64 + co] = s[px][co];
  }
}

__global__ __launch_bounds__(256) void prep_wt_k(const float* __restrict__ src,
    unsigned short* __restrict__ dst, int K, int N, int Kpad, int Npad)
{
  int idx = blockIdx.x * 256 + threadIdx.x;
  if (idx >= Kpad * Npad) return;
  int n = idx / Kpad, k = idx - n * Kpad;
  float v = (k < K && n < N) ? src[(size_t)k * N + n] : 0.f;
  dst[idx] = f2b(v);
}

// ---------------------------------------------------------------------------
// MFMA helpers (verified geometry, M=64)
// ---------------------------------------------------------------------------
template<int NT, int KT>
__device__ __forceinline__ void mfma_compute(
    const unsigned short* __restrict__ aBase, int AS,
    const unsigned short* __restrict__ WT, int Kpad,
    int n0, int lane, f32x4 (&acc)[4][NT])
{
  const int lr = lane & 15;
  const int lc = lane >> 4;
  #pragma unroll
  for (int m = 0; m < 4; ++m)
    #pragma unroll
    for (int j = 0; j < NT; ++j) acc[m][j] = (f32x4){0.f, 0.f, 0.f, 0.f};

  const unsigned short* aP = aBase + lr * AS + lc * 8;
  const unsigned short* bP = WT + (size_t)(n0 + lr) * Kpad + lc * 8;

  constexpr int KCH = (KT >= 4) ? 4 : KT;
  #pragma unroll
  for (int kc = 0; kc < KT; kc += KCH) {
    us8 breg[KCH][NT];
    #pragma unroll
    for (int kk = 0; kk < KCH; ++kk)
      #pragma unroll
      for (int j = 0; j < NT; ++j)
        breg[kk][j] = *(const us8*)(bP + (size_t)j * 16 * Kpad + (kc + kk) * 32);
    #pragma unroll
    for (int kc2 = 0; kc2 < KCH; ++kc2) {
      us8 a0[4];
      #pragma unroll
      for (int m = 0; m < 4; ++m)
        a0[m] = *(const us8*)(aP + (m * 16) * AS + (kc + kc2) * 32);
      #pragma unroll
      for (int m = 0; m < 4; ++m)
        #pragma unroll
        for (int j = 0; j < NT; ++j)
          acc[m][j] = MF(a0[m], breg[kc2][j], acc[m][j]);
    }
  }
}

template<int NT, bool RELU>
__device__ __forceinline__ void mfma_store(
    const f32x4 (&acc)[4][NT], const float* __restrict__ bias,
    unsigned short* __restrict__ dBase, int DS, int dCol0, int n0, int lane)
{
  const int lr = lane & 15;
  const int lc = lane >> 4;
  #pragma unroll
  for (int j = 0; j < NT; ++j) {
    int n = n0 + j * 16 + lr;
    float bv = bias[n];
    #pragma unroll
    for (int m = 0; m < 4; ++m)
      #pragma unroll
      for (int r = 0; r < 4; ++r) {
        float v = acc[m][j][r] + bv;
        if (RELU) v = fmaxf(v, 0.f);
        dBase[(m * 16 + lc * 4 + r) * DS + dCol0 + n] = f2b(v);
      }
  }
}

template<int KT>
__device__ __forceinline__ void mfma_out3w(
    const unsigned short* __restrict__ aBase, int AS,
    const unsigned short* __restrict__ WT, int Kpad,
    const float* __restrict__ bias, float (*dst)[4], int mtile, int lane)
{
  const int lr = lane & 15;
  const int lc = lane >> 4;
  f32x4 acc = (f32x4){0.f, 0.f, 0.f, 0.f};
  const unsigned short* aP = aBase + (mtile * 16 + lr) * AS + lc * 8;
  const unsigned short* bP = WT + (size_t)lr * Kpad + lc * 8;

  constexpr int KCH = (KT >= 4) ? 4 : KT;
  #pragma unroll
  for (int kc = 0; kc < KT; kc += KCH) {
    us8 breg[KCH];
    #pragma unroll
    for (int kk = 0; kk < KCH; ++kk)
      breg[kk] = *(const us8*)(bP + (kc + kk) * 32);
    #pragma unroll
    for (int kk = 0; kk < KCH; ++kk) {
      us8 a = *(const us8*)(aP + (kc + kk) * 32);
      acc = MF(a, breg[kk], acc);
    }
  }
  if (lr < 3) {
    float bv = bias[lr];
    #pragma unroll
    for (int r = 0; r < 4; ++r)
      dst[mtile * 16 + lc * 4 + r][lr] = acc[r] + bv;
  }
}

// ---------------------------------------------------------------------------
// Shared helpers
// ---------------------------------------------------------------------------
__device__ __forceinline__ void nearest_idx(float gy, float gx, int& iy, int& ix)
{
  float fy = (gy + 1.f) * (HL * 0.5f) - 0.5f;
  float fx = (gx + 1.f) * (WL * 0.5f) - 0.5f;
  iy = min(max((int)floorf(fy + 0.5f), 0), HL - 1);
  ix = min(max((int)floorf(fx + 0.5f), 0), WL - 1);
}

__device__ __forceinline__ float bilinear_lr(const float* __restrict__ lrimg,
                                             int b, int ch, float gy, float gx)
{
  float x = (gx + 1.f) * (WL * 0.5f) - 0.5f;
  float y = (gy + 1.f) * (HL * 0.5f) - 0.5f;
  float xf = floorf(x), yf = floorf(y);
  float wx = x - xf, wy = y - yf;
  int x0i = min(max((int)xf,     0), WL - 1);
  int x1i = min(max((int)xf + 1, 0), WL - 1);
  int y0i = min(max((int)yf,     0), HL - 1);
  int y1i = min(max((int)yf + 1, 0), HL - 1);
  const float* img = lrimg + ((size_t)b * 3 + ch) * PLANE;
  float v00 = img[y0i * WL + x0i], v01 = img[y0i * WL + x1i];
  float v10 = img[y1i * WL + x0i], v11 = img[y1i * WL + x1i];
  return v00 * (1.f - wx) * (1.f - wy) + v01 * wx * (1.f - wy)
       + v10 * (1.f - wx) * wy + v11 * wx * wy;
}

// ---------------------------------------------------------------------------
// Pass 1 (v3): conv_s_k-style classifier. 1 thread = 1 pixel; NO LDS, NO
// barriers, NO runtime-indexed private arrays. Weights are wave-uniform
// (broadcast loads); features re-read per j-block from L1. FP order matches
// all passing rounds: k ascending per output, logits j-ascending.
// ---------------------------------------------------------------------------
template<int JB>
__device__ __forceinline__ void cls_block(
    const float* __restrict__ fp,     // per-pixel feature row [64]
    float e0, float e1, float e2, float e3,
    const float* __restrict__ cw1, const float* __restrict__ cb1,
    const float* __restrict__ cw2,
    int j0, float& l0, float& l1)
{
  float acc[JB];
  #pragma unroll
  for (int j = 0; j < JB; ++j) acc[j] = cb1[j0 + j];
  #pragma unroll 4
  for (int kq = 0; kq < 16; ++kq) {
    float4 a4 = *(const float4*)(fp + kq * 4);
    float av[4] = {a4.x, a4.y, a4.z, a4.w};
    #pragma unroll
    for (int kk = 0; kk < 4; ++kk) {
      const float* wr = cw1 + (size_t)(kq * 4 + kk) * 64 + j0;
      float a = av[kk];
      #pragma unroll
      for (int j = 0; j < JB; ++j) acc[j] += a * wr[j];
    }
  }
  {
    const float* wr = cw1 + (size_t)64 * 64 + j0;
    #pragma unroll
    for (int j = 0; j < JB; ++j) acc[j] += e0 * wr[j];
    wr += 64;
    #pragma unroll
    for (int j = 0; j < JB; ++j) acc[j] += e1 * wr[j];
    wr += 64;
    #pragma unroll
    for (int j = 0; j < JB; ++j) acc[j] += e2 * wr[j];
    wr += 64;
    #pragma unroll
    for (int j = 0; j < JB; ++j) acc[j] += e3 * wr[j];
  }
  #pragma unroll
  for (int j = 0; j < JB; ++j) {
    float h = fmaxf(acc[j], 0.f);
    l0 += h * cw2[(j0 + j) * 2 + 0];
    l1 += h * cw2[(j0 + j) * 2 + 1];
  }
}

__global__ __launch_bounds__(256, 4) void cls_gate_k(
    const float* __restrict__ featT, const float* __restrict__ coord,
    const float* __restrict__ cell,
    const float* __restrict__ cw1, const float* __restrict__ cb1,
    const float* __restrict__ cw2, const float* __restrict__ cb2,
    int* __restrict__ counters, unsigned* __restrict__ easyList,
    unsigned* __restrict__ hardList)
{
  const int g = blockIdx.x * 256 + threadIdx.x;   // exact grid: NPIX/256
  const int b = g / (HO * WO);
  const float gy = coord[(size_t)g * 2 + 0];
  const float gx = coord[(size_t)g * 2 + 1];
  int iy, ix; nearest_idx(gy, gx, iy, ix);
  const float* fp = featT + (((size_t)b * PLANE) + iy * WL + ix) * 64;

  float cy = (2.f * iy + 1.f) / HL - 1.f;
  float cx = (2.f * ix + 1.f) / WL - 1.f;
  float e0 = (gy - cy) * HL;
  float e1 = (gx - cx) * WL;
  float e2 = cell[(size_t)g * 2 + 0] * HL;
  float e3 = cell[(size_t)g * 2 + 1] * WL;

  float l0 = cb2[0], l1 = cb2[1];
  cls_block<32>(fp, e0, e1, e2, e3, cw1, cb1, cw2, 0,  l0, l1);
  cls_block<32>(fp, e0, e1, e2, e3, cw1, cb1, cw2, 32, l0, l1);
  bool hard = (l1 > l0);

  // per-wave compaction
  unsigned long long mh = __ballot(hard);
  int lane = threadIdx.x & 63;
  int nh = __popcll(mh);
  int baseH = 0, baseE = 0;
  if (lane == 0) {
    baseH = atomicAdd(&counters[1], nh);
    baseE = atomicAdd(&counters[0], 64 - nh);
  }
  baseH = __shfl(baseH, 0);
  baseE = __shfl(baseE, 0);
  unsigned long long below = (1ull << lane) - 1ull;
  int hb = __popcll(mh & below);
  if (hard) hardList[baseH + hb] = (unsigned)g;
  else      easyList[baseE + (lane - hb)] = (unsigned)g;
}

// ---------------------------------------------------------------------------
// Gather helper: build bf16 inp row for pixel g into sInpB[p][0..103]
// ---------------------------------------------------------------------------
__device__ __forceinline__ void build_inp_row(
    const float* __restrict__ featT, const float* __restrict__ coord,
    const float* __restrict__ cell, unsigned g, int p, int q8,
    unsigned short (*sInpB)[104])
{
  int b = g / (HO * WO);
  float gy = coord[(size_t)g * 2 + 0];
  float gx = coord[(size_t)g * 2 + 1];
  int iy, ix; nearest_idx(gy, gx, iy, ix);
  const float* fpt = featT + (((size_t)b * PLANE) + iy * WL + ix) * 64 + q8 * 8;
  float4 u0 = *(const float4*)fpt;
  float4 u1 = *(const float4*)(fpt + 4);
  us8 pk;
  pk[0]=f2b(u0.x); pk[1]=f2b(u0.y); pk[2]=f2b(u0.z); pk[3]=f2b(u0.w);
  pk[4]=f2b(u1.x); pk[5]=f2b(u1.y); pk[6]=f2b(u1.z); pk[7]=f2b(u1.w);
  *(us8*)&sInpB[p][q8 * 8] = pk;
  if (q8 == 0) {
    float cy = (2.f * iy + 1.f) / HL - 1.f;
    float cx = (2.f * ix + 1.f) / WL - 1.f;
    float e0 = (gy - cy) * HL, e1 = (gx - cx) * WL;
    float e2 = cell[(size_t)g * 2 + 0] * HL, e3 = cell[(size_t)g * 2 + 1] * WL;
    us4 pe; pe[0]=f2b(e0); pe[1]=f2b(e1); pe[2]=f2b(e2); pe[3]=f2b(e3);
    *(us4*)&sInpB[p][64] = pe;
  }
  if (q8 == 1) {
    us4 z = (us4){0,0,0,0};
    #pragma unroll
    for (int c = 0; c < 9; ++c) *(us4*)&sInpB[p][68 + c * 4] = z;
  }
}

// ---------------------------------------------------------------------------
// Pass 2: light MLP over easy list (64 px / block, 256 thr)
// ---------------------------------------------------------------------------
__global__ __launch_bounds__(256, 4) void light_k(
    const float* __restrict__ featT, const float* __restrict__ coord,
    const float* __restrict__ cell,  const float* __restrict__ lrimg,
    const float* __restrict__ lb1, const float* __restrict__ lb2,
    const float* __restrict__ lb3,
    const unsigned short* __restrict__ lw1T, const unsigned short* __restrict__ lw2T,
    const unsigned short* __restrict__ lw3T,
    const int* __restrict__ counters, const unsigned* __restrict__ list,
    float* __restrict__ out)
{
  const int nE = counters[0];
  const int g0 = blockIdx.x * 64;
  if (g0 >= nE) return;

  __shared__ unsigned short sInpB[64][104];
  __shared__ unsigned short sL1[64][72];
  __shared__ unsigned short sL2[64][72];
  __shared__ float sP[64][4];
  __shared__ unsigned sIdx[64];

  const int t = threadIdx.x, lane = t & 63, w = t >> 6;

  {
    const int p = t >> 2, q = t & 3;
    int i = g0 + p; if (i > nE - 1) i = nE - 1;
    unsigned g = list[i];
    if (q == 0) sIdx[p] = g;
    build_inp_row(featT, coord, cell, g, p, q * 2,     sInpB);
    build_inp_row(featT, coord, cell, g, p, q * 2 + 1, sInpB);
  }
  __syncthreads();

  { f32x4 acc[4][1];
    mfma_compute<1, 3>(&sInpB[0][0], 104, lw1T, 96, w * 16, lane, acc);
    mfma_store<1, true>(acc, lb1, &sL1[0][0], 72, 0, w * 16, lane); }
  __syncthreads();
  { f32x4 acc[4][1];
    mfma_compute<1, 2>(&sL1[0][0], 72, lw2T, 64, w * 16, lane, acc);
    mfma_store<1, true>(acc, lb2, &sL2[0][0], 72, 0, w * 16, lane); }
  __syncthreads();
  mfma_out3w<2>(&sL2[0][0], 72, lw3T, 64, lb3, sP, w, lane);
  __syncthreads();

  if (t < 192) {
    int p = t / 3, ch = t % 3;
    int i = g0 + p;
    if (i < nE) {
      unsigned g = sIdx[p];
      int b = g / (HO * WO);
      int rem = g % (HO * WO);
      int oy = rem / WO, ox = rem % WO;
      float gy = coord[(size_t)g * 2 + 0];
      float gx = coord[(size_t)g * 2 + 1];
      float v = bilinear_lr(lrimg, b, ch, gy, gx);
      out[(((size_t)b * 3 + ch) * HO + oy) * WO + ox] = sP[p][ch] + v;
    }
  }
}

// ---------------------------------------------------------------------------
// Pass 3: heavy MLP over hard list (64 px / block, 512 thr)
// ---------------------------------------------------------------------------
__global__ __launch_bounds__(512, 4) void heavy_k(
    const float* __restrict__ featT, const float* __restrict__ coord,
    const float* __restrict__ cell,  const float* __restrict__ lrimg,
    const float* __restrict__ hb1, const float* __restrict__ hmb,
    const float* __restrict__ hbo,
    const unsigned short* __restrict__ hw1T, const unsigned short* __restrict__ hm0T,
    const unsigned short* __restrict__ hm1T, const unsigned short* __restrict__ hwoT,
    const int* __restrict__ counters, const unsigned* __restrict__ list,
    float* __restrict__ out)
{
  const int nH = counters[1];
  const int g0 = blockIdx.x * 64;
  if (g0 >= nH) return;

  __shared__ unsigned short sAct[64][264];
  __shared__ unsigned short sInpB[64][104];
  __shared__ float sP[64][4];
  __shared__ unsigned sIdx[64];

  const int t = threadIdx.x, lane = t & 63, w = t >> 6;

  {
    const int p = t >> 3, q = t & 7;
    int i = g0 + p; if (i > nH - 1) i = nH - 1;
    unsigned g = list[i];
    if (q == 0) sIdx[p] = g;
    build_inp_row(featT, coord, cell, g, p, q, sInpB);
  }
  __syncthreads();

  { f32x4 acc[4][2];
    mfma_compute<2, 3>(&sInpB[0][0], 104, hw1T, 96, w * 32, lane, acc);
    mfma_store<2, true>(acc, hb1, &sAct[0][0], 264, 0, w * 32, lane); }
  __syncthreads();
  { f32x4 acc[4][2];
    mfma_compute<2, 8>(&sAct[0][0], 264, hm0T, 256, w * 32, lane, acc);
    __syncthreads();
    mfma_store<2, true>(acc, hmb, &sAct[0][0], 264, 0, w * 32, lane); }
  __syncthreads();
  { f32x4 acc[4][2];
    mfma_compute<2, 8>(&sAct[0][0], 264, hm1T, 256, w * 32, lane, acc);
    __syncthreads();
    mfma_store<2, true>(acc, hmb + 256, &sAct[0][0], 264, 0, w * 32, lane); }
  __syncthreads();
  if (w < 4) mfma_out3w<8>(&sAct[0][0], 264, hwoT, 256, hbo, sP, w, lane);
  __syncthreads();

  if (t < 192) {
    int p = t / 3, ch = t % 3;
    int i = g0 + p;
    if (i < nH) {
      unsigned g = sIdx[p];
      int b = g / (HO * WO);
      int rem = g % (HO * WO);
      int oy = rem / WO, ox = rem % WO;
      float gy = coord[(size_t)g * 2 + 0];
      float gx = coord[(size_t)g * 2 + 1];
      float v = bilinear_lr(lrimg, b, ch, gy, gx);
      out[(((size_t)b * 3 + ch) * HO + oy) * WO + ox] = sP[p][ch] + v;
    }
  }
}

__global__ void finalize_k(const int* __restrict__ counters, float* __restrict__ out)
{
  out[(size_t)NPIX * 3] = (float)(counters[0]) / (float)NPIX;
}

// ---------------------------------------------------------------------------
extern "C" void kernel_launch(void* const* d_in, const int* in_sizes, int n_in,
                              void* d_out, int out_size, void* d_ws, size_t ws_size,
                              hipStream_t stream)
{
  const float* lr       = (const float*)d_in[0];
  const float* coord    = (const float*)d_in[1];
  const float* cell     = (const float*)d_in[2];
  const float* enc_w_in = (const float*)d_in[3];
  const float* enc_b_in = (const float*)d_in[4];
  const float* enc_rw   = (const float*)d_in[5];
  const float* enc_rb   = (const float*)d_in[6];
  const float* cw1      = (const float*)d_in[7];
  const float* cb1      = (const float*)d_in[8];
  const float* cw2      = (const float*)d_in[9];
  const float* cb2      = (const float*)d_in[10];
  const float* lw1      = (const float*)d_in[11];
  const float* lb1      = (const float*)d_in[12];
  const float* lw2      = (const float*)d_in[13];
  const float* lb2      = (const float*)d_in[14];
  const float* lw3      = (const float*)d_in[15];
  const float* lb3      = (const float*)d_in[16];
  const float* hw1      = (const float*)d_in[17];
  const float* hb1      = (const float*)d_in[18];
  const float* hmw      = (const float*)d_in[19];
  const float* hmb      = (const float*)d_in[20];
  const float* hwo      = (const float*)d_in[21];
  const float* hbo      = (const float*)d_in[22];
  float* out = (float*)d_out;

  char* ws = (char*)d_ws;
  float* xA    = (float*)(ws + 1024);
  float* tmp   = xA  + FEAT_ELEMS;
  float* xB    = tmp + FEAT_ELEMS;
  float* featT = tmp;                 // aliases tmp (free after last res conv)
  unsigned short* wb = (unsigned short*)(xB + FEAT_ELEMS);
  unsigned short* lw1T = wb;              // 64*96
  unsigned short* lw2T = lw1T + 64*96;    // 64*64
  unsigned short* lw3T = lw2T + 64*64;    // 16*64
  unsigned short* hw1T = lw3T + 16*64;    // 256*96
  unsigned short* hm0T = hw1T + 256*96;   // 256*256
  unsigned short* hm1T = hm0T + 65536;    // 256*256
  unsigned short* hwoT = hm1T + 65536;    // 16*256
  const size_t nb16 = 64*96 + 64*64 + 16*64 + 256*96 + 2*65536 + 16*256; // 171008
  float* cwIn  = (float*)(wb + nb16);     // 27*64 = 1728
  float* cwRes = cwIn + 1728;             // 8 * 36864
  size_t need = 1024 + 3 * FEAT_ELEMS * sizeof(float)
              + nb16 * 2 + (1728 + 8 * 36864) * sizeof(float);
  if (ws_size < need) return;

  // lists/counters alias xB (free after final residual conv)
  int*      counters = (int*)xB;
  unsigned* easyList = (unsigned*)(xB + 16);
  unsigned* hardList = easyList + NPIX;

  auto prep = [&](const float* s, unsigned short* d, int K, int N, int Kp, int Np) {
    int tot = Kp * Np;
    prep_wt_k<<<(tot + 255) / 256, 256, 0, stream>>>(s, d, K, N, Kp, Np);
  };
  prep(lw1, lw1T, 68, 64, 96, 64);
  prep(lw2, lw2T, 64, 64, 64, 64);
  prep(lw3, lw3T, 64, 3, 64, 16);
  prep(hw1, hw1T, 68, 256, 96, 256);
  prep(hmw,         hm0T, 256, 256, 256, 256);
  prep(hmw + 65536, hm1T, 256, 256, 256, 256);
  prep(hwo, hwoT, 256, 3, 256, 16);

  prep_convw_k<<<(1728 + 255) / 256, 256, 0, stream>>>(enc_w_in, cwIn, 3);
  for (int l = 0; l < 8; ++l)
    prep_convw_k<<<(36864 + 255) / 256, 256, 0, stream>>>(
        enc_rw + (size_t)l * 36864, cwRes + (size_t)l * 36864, 64);

  // --- encoder (fp32; ends with feat in xA) ---
  dim3 cgrid(36, 16, 2);
  conv_s_k<3, 4, false, false><<<cgrid, 256, 0, stream>>>(lr, cwIn, enc_b_in, nullptr, xA);

  float* cur = xA; float* oth = xB;
  for (int i = 0; i < 4; ++i) {
    const float* wp0 = cwRes + (size_t)(2 * i)     * 36864;
    const float* wp1 = cwRes + (size_t)(2 * i + 1) * 36864;
    const float* b0 = enc_rb + i * 128;
    const float* b1 = b0 + 64;
    conv_s_k<64, 4, true,  false><<<cgrid, 256, 0, stream>>>(cur, wp0, b0, nullptr, tmp);
    conv_s_k<64, 4, false, true ><<<cgrid, 256, 0, stream>>>(tmp, wp1, b1, cur, oth);
    float* sw2 = cur; cur = oth; oth = sw2;
  }
  // cur == xA here -> xB free for lists

  nchw_to_nhwc_k<<<dim3(144, 2), 256, 0, stream>>>(cur, featT);

  hipMemsetAsync(counters, 0, 16, stream);

  cls_gate_k<<<NPIX / 256, 256, 0, stream>>>(featT, coord, cell,
      cw1, cb1, cw2, cb2, counters, easyList, hardList);

  light_k<<<NPIX / 64, 256, 0, stream>>>(featT, coord, cell, lr,
      lb1, lb2, lb3, lw1T, lw2T, lw3T, counters, easyList, out);

  heavy_k<<<NPIX / 64, 512, 0, stream>>>(featT, coord, cell, lr,
      hb1, hmb, hbo, hw1T, hm0T, hm1T, hwoT, counters, hardList, out);

  finalize_k<<<1, 1, 0, stream>>>(counters, out);
}